// Round 7
// baseline (339.700 us; speedup 1.0000x reference)
//
#include <hip/hip_runtime.h>

// MomentumLSTM R7: balanced 2-wave hybrid blocks.
// Block = 128 threads = 2 identical hybrid waves; tile = 32 batch cols.
// Wave W owns L1 units [32W,32W+32) (4 gate-packed mtiles) AND L2 units
// [16W,16W+16) (2 mtiles). Weights in registers; ktile slots pre-permuted at
// staging (kt = slot ^ 2W) so the hot loop is {own0,own1,partner0,partner1}
// with no branches. Own h-frags persist in registers (permlane32_swap build);
// partner frags + x via tiny parity-double-buffered LDS, all lane-contiguous.
// Order per iter: L2(t-1) [uses h1(t-1) regs before overwrite] -> L1(t) -> barrier.
// L2 bias + Wih1/bias frags live in LDS to fit <=256 VGPR.

using f32x16 = __attribute__((ext_vector_type(16))) float;
using s16x8  = __attribute__((ext_vector_type(8)))  short;
using uint2v = __attribute__((ext_vector_type(2)))  unsigned int;
typedef unsigned int uint;
typedef unsigned short ushort;

#define THREADS 128
#define NBLOCKS 1024
#define L2E 1.44269504f

__device__ __forceinline__ float fsig(float v) {
    float e = __builtin_amdgcn_exp2f(-L2E * v);
    return __builtin_amdgcn_rcpf(1.0f + e);
}
// PRE-SCALED preacts: zi,zf,zo = -L2E*gate, zg = +2L2E*gate.
__device__ __forceinline__ void lstm_act_pre(float zi, float zf, float zg, float zo,
                                             float& cs, float& hv) {
    float ei = __builtin_amdgcn_exp2f(zi);
    float ef = __builtin_amdgcn_exp2f(zf);
    float eg = __builtin_amdgcn_exp2f(zg);
    float eo = __builtin_amdgcn_exp2f(zo);
    float ai = 1.0f + ei, af = 1.0f + ef;
    float r0 = __builtin_amdgcn_rcpf(ai * af);
    float iv = r0 * af, fv = r0 * ai;                 // sigmoid(i), sigmoid(f)
    float ag = 1.0f + eg, ao = 1.0f + eo;
    float r1 = __builtin_amdgcn_rcpf(ag * ao);
    float gv = __builtin_fmaf(-2.0f * r1, ao, 1.0f);  // tanh(g)
    float ov = r1 * ag;                               // sigmoid(o)
    float c = __builtin_fmaf(fv, cs, iv * gv);
    cs = c;
    float et = __builtin_amdgcn_exp2f((2.0f * L2E) * c);
    float tt = __builtin_fmaf(-2.0f, __builtin_amdgcn_rcpf(1.0f + et), 1.0f);
    hv = ov * tt;
}
__device__ __forceinline__ ushort bfhi(float w) {     // RNE bf16
    uint u = __builtin_bit_cast(uint, w);
    return (ushort)((u + 0x7fffu + ((u >> 16) & 1u)) >> 16);
}
__device__ __forceinline__ uint pkbf(float a, float b) {
    uint r;
    asm("v_cvt_pk_bf16_f32 %0, %1, %2" : "=v"(r) : "v"(a), "v"(b));
    return r;
}
__device__ __forceinline__ uint4 pack8(const ushort v[8]) {
    return make_uint4(v[0] | ((uint)v[1] << 16), v[2] | ((uint)v[3] << 16),
                      v[4] | ((uint)v[5] << 16), v[6] | ((uint)v[7] << 16));
}
#define MFMA32(a, b, c) \
    __builtin_amdgcn_mfma_f32_32x32x16_bf16(__builtin_bit_cast(s16x8, (a)), \
        __builtin_bit_cast(s16x8, (b)), (c), 0, 0, 0)
#define PLSWAP(a, b) __builtin_amdgcn_permlane32_swap((a), (b), false, false)

__global__ void __launch_bounds__(THREADS, 2) lstm_kernel(
    const float* __restrict__ x,
    const float* __restrict__ Wih1, const float* __restrict__ Whh1,
    const float* __restrict__ bih1, const float* __restrict__ bhh1,
    const float* __restrict__ Wih2, const float* __restrict__ Whh2,
    const float* __restrict__ bih2, const float* __restrict__ bhh2,
    const float* __restrict__ Wd, const float* __restrict__ bd,
    const float* __restrict__ Wo, const float* __restrict__ bo,
    float* __restrict__ out)
{
    __shared__ uint4 sH1[2][4][64];   // h1 B-frags [parity][global ktile][lane]
    __shared__ uint4 sH2[2][2][64];   // h2 B-frags [parity][global ktile][lane]
    __shared__ uint4 sXW[2][4][64];   // Wih1+bias A-frags [W][mtile][lane]
    __shared__ uint4 sX[2][32];       // packed x [parity][col]
    __shared__ float sB2[2][2][32];   // L2 bias (pre-scaled) [W][mm][row]
    __shared__ float sWd[512];
    __shared__ float sBd[16], sWo[16], sBo[1];
    __shared__ float sHs[1024];       // head scratch [col][unit]

    const int tid = threadIdx.x;
    const int lane = tid & 63;
    const int W = tid >> 6;                     // 0 or 1
    const int hh = lane >> 5, n = lane & 31;
    const int bbase = blockIdx.x * 32;

    for (int i = tid; i < 512; i += THREADS) sWd[i] = Wd[i];
    if (tid < 16) { sBd[tid] = bd[tid]; sWo[tid] = Wo[tid]; }
    if (tid == 0) sBo[0] = bo[0];
    {
        uint4 z = make_uint4(0, 0, 0, 0);
        uint4* p1 = &sH1[1][0][0];
        for (int i = tid; i < 256; i += THREADS) p1[i] = z;
        uint4* p2 = &sH2[1][0][0];
        for (int i = tid; i < 128; i += THREADS) p2[i] = z;
    }

    // ---- stage weights into registers (gate-in-row mtiles, pre-scaled) ----
    // A-frag row = n: gate = n>>3, unit3 = n&7. Slot j <-> global ktile j^(2W).
    const int gate = n >> 3, u3 = n & 7;
    const float sc = (gate == 2) ? (2.0f * L2E) : (-L2E);

    uint4 whh1[4][4], wih2[2][4], whh2[2][2];
#pragma unroll
    for (int m = 0; m < 4; ++m) {
        int G = gate * 64 + 32 * W + 8 * m + u3;
#pragma unroll
        for (int j = 0; j < 4; ++j) {
            int kt = j ^ (2 * W);
            const float* src = Whh1 + G * 64 + kt * 16 + hh * 8;
            ushort v[8];
#pragma unroll
            for (int e = 0; e < 8; ++e) v[e] = bfhi(src[e] * sc);
            whh1[m][j] = pack8(v);
        }
        float b1 = (bih1[G] + bhh1[G]) * sc;
        ushort v[8];
#pragma unroll
        for (int e = 0; e < 8; ++e)
            v[e] = (hh == 0) ? bfhi((e < 7) ? Wih1[G * 7 + e] * sc : b1) : (ushort)0;
        sXW[W][m][lane] = pack8(v);
    }
#pragma unroll
    for (int mm = 0; mm < 2; ++mm) {
        int G = gate * 32 + 16 * W + 8 * mm + u3;
#pragma unroll
        for (int j = 0; j < 4; ++j) {
            int kt = j ^ (2 * W);
            const float* src = Wih2 + G * 64 + kt * 16 + hh * 8;
            ushort v[8];
#pragma unroll
            for (int e = 0; e < 8; ++e) v[e] = bfhi(src[e] * sc);
            wih2[mm][j] = pack8(v);
        }
#pragma unroll
        for (int j = 0; j < 2; ++j) {
            int kt = j ^ W;
            const float* src = Whh2 + G * 32 + kt * 16 + hh * 8;
            ushort v[8];
#pragma unroll
            for (int e = 0; e < 8; ++e) v[e] = bfhi(src[e] * sc);
            whh2[mm][j] = pack8(v);
        }
        if (hh == 0) sB2[W][mm][n] = (bih2[G] + bhh2[G]) * sc;
    }

    const float* xp = x + (size_t)(bbase + lane) * 420;
    if (W == 1 && lane < 32) {                  // pack x(0) -> parity 0
        float x0[7];
#pragma unroll
        for (int d = 0; d < 7; ++d) x0[d] = xp[d];
        sX[0][lane] = make_uint4(pkbf(x0[0], x0[1]), pkbf(x0[2], x0[3]),
                                 pkbf(x0[4], x0[5]), pkbf(x0[6], 1.0f));
    }

    float c1[16], c2[8];
#pragma unroll
    for (int i = 0; i < 16; ++i) c1[i] = 0.f;
#pragma unroll
    for (int i = 0; i < 8; ++i) c2[i] = 0.f;
    uint4 h1o0 = make_uint4(0, 0, 0, 0), h1o1 = make_uint4(0, 0, 0, 0);
    uint4 h2o = make_uint4(0, 0, 0, 0);
    float h2v[2][4];
    const int pW = 2 * (1 - W);

    __syncthreads();

    // L2 step body (bias-init from LDS, 6 MFMA, 4+4 acts)
    auto l2body = [&](uint4 h1p0, uint4 h1p1, uint4 h2p) {
#pragma unroll
        for (int mm = 0; mm < 2; ++mm) {
            float4 b0 = *(const float4*)&sB2[W][mm][4 * hh + 0];
            float4 b1q = *(const float4*)&sB2[W][mm][4 * hh + 8];
            float4 b2q = *(const float4*)&sB2[W][mm][4 * hh + 16];
            float4 b3q = *(const float4*)&sB2[W][mm][4 * hh + 24];
            f32x16 c;
            c[0] = b0.x;  c[1] = b0.y;  c[2] = b0.z;  c[3] = b0.w;
            c[4] = b1q.x; c[5] = b1q.y; c[6] = b1q.z; c[7] = b1q.w;
            c[8] = b2q.x; c[9] = b2q.y; c[10] = b2q.z; c[11] = b2q.w;
            c[12] = b3q.x; c[13] = b3q.y; c[14] = b3q.z; c[15] = b3q.w;
            c = MFMA32(wih2[mm][0], h1o0, c);
            c = MFMA32(wih2[mm][1], h1o1, c);
            c = MFMA32(wih2[mm][2], h1p0, c);
            c = MFMA32(wih2[mm][3], h1p1, c);
            c = MFMA32(whh2[mm][0], h2o, c);
            c = MFMA32(whh2[mm][1], h2p, c);
#pragma unroll
            for (int s = 0; s < 4; ++s)
                lstm_act_pre(c[s], c[s + 4], c[s + 8], c[s + 12],
                             c2[mm * 4 + s], h2v[mm][s]);
        }
    };

    for (int t = 0; t < 60; ++t) {
        const int pr = (t + 1) & 1;             // parity holding state (t-1)
        uint4 h1p0 = sH1[pr][pW + 0][lane];
        uint4 h1p1 = sH1[pr][pW + 1][lane];
        uint4 xB = sX[t & 1][n];

        // ===== L2 (step t-1): consumes h1(t-1) regs BEFORE L1 overwrites =====
        if (t > 0) {
            uint4 h2p = sH2[t & 1][1 - W][lane];
            l2body(h1p0, h1p1, h2p);
            uint Pa = pkbf(h2v[0][0], h2v[0][1]);
            uint Pb = pkbf(h2v[1][0], h2v[1][1]);
            uint Pc = pkbf(h2v[0][2], h2v[0][3]);
            uint Pd = pkbf(h2v[1][2], h2v[1][3]);
            uint2v sA = PLSWAP(Pa, Pb);
            uint2v sB = PLSWAP(Pc, Pd);
            h2o = make_uint4(sA[0], sB[0], sA[1], sB[1]);
            sH2[pr][W][lane] = h2o;             // publish h2(t-1)
        }

        float xr[7];
        if (W == 1 && lane < 32 && t < 59) {    // prefetch x(t+1)
#pragma unroll
            for (int d = 0; d < 7; ++d) xr[d] = xp[(t + 1) * 7 + d];
        }

        // ===== L1 (step t) =====
        uint P0[4], P1[4];
#pragma unroll
        for (int m = 0; m < 4; ++m) {
            uint4 xw = sXW[W][m][lane];
            f32x16 c;
#pragma unroll
            for (int i = 0; i < 16; ++i) c[i] = 0.f;
            c = MFMA32(whh1[m][0], h1o0, c);
            c = MFMA32(whh1[m][1], h1o1, c);
            c = MFMA32(whh1[m][2], h1p0, c);
            c = MFMA32(whh1[m][3], h1p1, c);
            c = MFMA32(xw, xB, c);              // x-proj + bias (k=7 vs 1.0)
            float hv0, hv1, hv2, hv3;
            lstm_act_pre(c[0], c[4], c[8],  c[12], c1[m * 4 + 0], hv0);
            lstm_act_pre(c[1], c[5], c[9],  c[13], c1[m * 4 + 1], hv1);
            lstm_act_pre(c[2], c[6], c[10], c[14], c1[m * 4 + 2], hv2);
            lstm_act_pre(c[3], c[7], c[11], c[15], c1[m * 4 + 3], hv3);
            P0[m] = pkbf(hv0, hv1);
            P1[m] = pkbf(hv2, hv3);
        }
        {
            uint2v sA = PLSWAP(P0[0], P0[1]);
            uint2v sB = PLSWAP(P1[0], P1[1]);
            h1o0 = make_uint4(sA[0], sB[0], sA[1], sB[1]);
            sH1[t & 1][2 * W + 0][lane] = h1o0;
        }
        {
            uint2v sA = PLSWAP(P0[2], P0[3]);
            uint2v sB = PLSWAP(P1[2], P1[3]);
            h1o1 = make_uint4(sA[0], sB[0], sA[1], sB[1]);
            sH1[t & 1][2 * W + 1][lane] = h1o1;
        }
        if (W == 1 && lane < 32 && t < 59) {    // pack x(t+1)
            sX[pr][lane] = make_uint4(pkbf(xr[0], xr[1]), pkbf(xr[2], xr[3]),
                                      pkbf(xr[4], xr[5]), pkbf(xr[6], 1.0f));
        }
        __syncthreads();
    }

    // ===== final L2 step (t=59) =====
    {
        uint4 h1p0 = sH1[1][pW + 0][lane];
        uint4 h1p1 = sH1[1][pW + 1][lane];
        uint4 h2p = sH2[0][1 - W][lane];
        l2body(h1p0, h1p1, h2p);
#pragma unroll
        for (int mm = 0; mm < 2; ++mm)
#pragma unroll
            for (int s = 0; s < 4; ++s)
                sHs[n * 32 + 16 * W + 8 * mm + 4 * hh + s] = h2v[mm][s];
    }
    __syncthreads();

    // ===== dense head (wave 0) =====
    if (W == 0 && lane < 32) {
        const float* hcol = sHs + lane * 32;
        float a[16];
#pragma unroll
        for (int o = 0; o < 16; ++o) a[o] = sBd[o];
#pragma unroll 4
        for (int u = 0; u < 32; ++u) {
            float hvv = hcol[u];
#pragma unroll
            for (int o = 0; o < 16; ++o)
                a[o] = __builtin_fmaf(sWd[o * 32 + u], hvv, a[o]);
        }
        float rr = sBo[0];
#pragma unroll
        for (int o = 0; o < 16; ++o)
            rr = __builtin_fmaf(sWo[o], fmaxf(a[o], 0.0f), rr);
        out[bbase + lane] = fsig(rr);
    }
}

extern "C" void kernel_launch(void* const* d_in, const int* in_sizes, int n_in,
                              void* d_out, int out_size, void* d_ws, size_t ws_size,
                              hipStream_t stream) {
    const float* x    = (const float*)d_in[0];
    const float* Wih1 = (const float*)d_in[1];
    const float* Whh1 = (const float*)d_in[2];
    const float* bih1 = (const float*)d_in[3];
    const float* bhh1 = (const float*)d_in[4];
    const float* Wih2 = (const float*)d_in[5];
    const float* Whh2 = (const float*)d_in[6];
    const float* bih2 = (const float*)d_in[7];
    const float* bhh2 = (const float*)d_in[8];
    const float* Wd   = (const float*)d_in[9];
    const float* bd   = (const float*)d_in[10];
    const float* Wo   = (const float*)d_in[11];
    const float* bo   = (const float*)d_in[12];
    float* out = (float*)d_out;

    lstm_kernel<<<NBLOCKS, THREADS, 0, stream>>>(
        x, Wih1, Whh1, bih1, bhh1, Wih2, Whh2, bih2, bhh2, Wd, bd, Wo, bo, out);
}